// Round 1
// baseline (483.448 us; speedup 1.0000x reference)
//
#include <hip/hip_runtime.h>
#include <hip/hip_bf16.h>

// BilateralRotation: out[b,c] = R1[c] @ wkv[b,c] @ R2[c]
// R = Cayley(p) = (I - A)(I + A)^{-1}, A = 0.5(p - p^T)
// B=512, C=32, H=W=64. wkv/out fp32; compute in bf16 MFMA (abs threshold 0.108).
//
// R3: rot_kernel restructured for latency:
//   - A-fragments loaded DIRECTLY from global (no Wl staging, no W round-trip).
//     Per-lane 8x dwordx4 in frag layout; wave-pair duplication dedup'd by L1.
//   - 1 barrier/tile: UTl double-buffered; raw s_barrier + lgkmcnt(0) only
//     (NO vmcnt drain -> next-tile prefetch stays in flight across barrier).
//   - native bf16 converts (v_cvt_pk_bf16_f32) instead of 3-op manual RNE.
//   - TPB=16 -> grid 1024 = exactly 4 blocks/CU, half the R-staging overhead.

#define NHEADS 32
#define TILE_ELEMS 4096   // 64*64
#define TPB 16            // wkv tiles per rot block

typedef __attribute__((ext_vector_type(8))) short bf16x8;     // MFMA A/B frag
typedef __attribute__((ext_vector_type(16))) float f32x16;    // MFMA C/D (32x32)
typedef __attribute__((ext_vector_type(4))) unsigned short us4;

static __device__ __forceinline__ unsigned short f2bf(float f) {
    // native cast -> backend emits v_cvt_pk_bf16_f32 (RNE), 1 op vs 3
    return __builtin_bit_cast(unsigned short, __float2bfloat16(f));
}

// ---------------------------------------------------------------------------
// Kernel 1: Cayley. 64 blocks (32 left -> R1 row-major, 32 right -> R2
// TRANSPOSED). Register-resident Gauss-Jordan: thread (row, sl) owns
// M[row][16sl..16sl+15] and N[...] in VGPRs. Per iter k, only row k's slices
// + column-k factors pass through double-buffered LDS -> 1 barrier/iter.
// M = I+A has SPD symmetric part -> no pivoting needed.
// ---------------------------------------------------------------------------
__global__ __launch_bounds__(256) void cayley_kernel(
    const float* __restrict__ p_left, const float* __restrict__ p_right,
    unsigned short* __restrict__ ws_r1, unsigned short* __restrict__ ws_r2t) {
    __shared__ float P[64][68];       // stride 68: float4-aligned rows
    __shared__ float frowM[2][64];
    __shared__ float frowN[2][64];
    __shared__ float fcol[2][64];
    __shared__ float dinv_l[64];

    const int t = threadIdx.x;
    const int side = blockIdx.x >> 5;
    const int c = blockIdx.x & 31;
    const float* p = (side ? p_right : p_left) + c * TILE_ELEMS;

    // load p row-major (coalesced float4)
    for (int i = 0; i < 4; ++i) {
        int f = t + 256 * i;            // float4 index 0..1023
        int r = f >> 4, c4 = f & 15;
        *(float4*)&P[r][c4 * 4] = ((const float4*)p)[f];
    }
    __syncthreads();

    const int row = t & 63;
    const int sl  = t >> 6;
    const int jb  = sl * 16;

    // M = I + A, N = I - A in registers
    float mreg[16], nreg[16];
#pragma unroll
    for (int jj = 0; jj < 16; ++jj) {
        int j = jb + jj;
        float a = 0.5f * (P[row][j] - P[j][row]);
        float e = (row == j) ? 1.0f : 0.0f;
        mreg[jj] = e + a;
        nreg[jj] = e - a;
    }

    // Gauss-Jordan to diagonal; N -> diag(M) * R
    int buf = 0;
    for (int k = 0; k < 64; ++k) {
        const int kb = k >> 4, kk = k & 15;
        if (row == k) {
#pragma unroll
            for (int jj = 0; jj < 16; ++jj) {
                frowM[buf][jb + jj] = mreg[jj];
                frowN[buf][jb + jj] = nreg[jj];
            }
        }
        if (sl == kb) fcol[buf][row] = mreg[kk];
        __syncthreads();
        // safe single barrier: double-buffered staging; iter k+2 writes to
        // parity(k) only after barrier k+1, which postdates all iter-k reads.
        float pinv = __builtin_amdgcn_rcpf(frowM[buf][k]);
        float f = fcol[buf][row] * pinv;
        if (row != k) {
#pragma unroll
            for (int jj = 0; jj < 16; ++jj) {
                mreg[jj] -= f * frowM[buf][jb + jj];
                nreg[jj] -= f * frowN[buf][jb + jj];
            }
        }
        buf ^= 1;
    }

    if (sl == (row >> 4)) dinv_l[row] = __builtin_amdgcn_rcpf(mreg[row & 15]);
    __syncthreads();
    const float dinv = dinv_l[row];

    if (side == 0) {
        unsigned short* dst = ws_r1 + c * TILE_ELEMS;
#pragma unroll
        for (int q4 = 0; q4 < 4; ++q4) {
            us4 v;
#pragma unroll
            for (int q = 0; q < 4; ++q) v[q] = f2bf(nreg[q4 * 4 + q] * dinv);
            *(us4*)&dst[row * 64 + jb + q4 * 4] = v;
        }
    } else {
        unsigned short* dst = ws_r2t + c * TILE_ELEMS;
#pragma unroll
        for (int jj = 0; jj < 16; ++jj)
            dst[(jb + jj) * 64 + row] = f2bf(nreg[jj] * dinv);  // transposed
    }
}

// ---------------------------------------------------------------------------
// Kernel 2: 1024 blocks; block = (head c, 16 consecutive b). 4 waves, each a
// 32x32 quadrant. Per tile: U = W @ R2 (A direct-from-global regs, B = R2T
// rows), out = R1 @ U (B = UT rows, transposed via LDS from MFMA C-layout).
// UTl double-buffered -> single raw barrier per tile; lgkmcnt(0)-only barrier
// keeps the next tile's global prefetch in flight across it.
// LDS stride 72 shorts (144 B): b128 frag reads conflict-free.
// ---------------------------------------------------------------------------
__global__ __launch_bounds__(256, 4) void rot_kernel(
    const float* __restrict__ wkv,
    const unsigned short* __restrict__ ws_r1,
    const unsigned short* __restrict__ ws_r2t,
    float* __restrict__ out) {
    __shared__ unsigned short R1l[64][72];
    __shared__ unsigned short R2Tl[64][72];
    __shared__ unsigned short UTl[2][64][72];

    const int t = threadIdx.x;
    const int c = blockIdx.x & 31;
    const int bg = blockIdx.x >> 5;
    const size_t tile0 = (size_t)(bg * TPB) * NHEADS + c;   // flat (b,c) index

    // stage R1 / R2T once (bf16, coalesced 8B, L2-hot)
    {
        const us4* s1 = (const us4*)(ws_r1 + c * TILE_ELEMS);
        const us4* s2 = (const us4*)(ws_r2t + c * TILE_ELEMS);
        for (int i = 0; i < 4; ++i) {
            int f = t + 256 * i;
            int r = f >> 4, c4 = f & 15;
            *(us4*)&R1l[r][c4 * 4]  = s1[f];
            *(us4*)&R2Tl[r][c4 * 4] = s2[f];
        }
    }

    const int lane = t & 63;
    const int wave = t >> 6;
    const int l31 = lane & 31;
    const int lhi = lane >> 5;
    const int wr = (wave & 1) * 32;
    const int wc = (wave >> 1) * 32;
    const int m = wr + l31;
    const int n = wc + l31;

    // per-lane direct A-operand source: row m, 8-col chunk at kb*16 + lhi*8.
    // Each 64B line of the tile is requested exactly once per wave (halves by
    // the paired dwordx4); wave-pair duplication is an L1/MSHR hit.
    const float* asrc = wkv + tile0 * TILE_ELEMS + m * 64 + lhi * 8;

    // prefetch tile 0's A-fragments (fp32) into registers
    float4 pf[8];
#pragma unroll
    for (int kb = 0; kb < 4; ++kb) {
        pf[2 * kb]     = *(const float4*)(asrc + kb * 16);
        pf[2 * kb + 1] = *(const float4*)(asrc + kb * 16 + 4);
    }

    // raw barrier: drain LDS writes only; tile-0 loads may stay in flight
    asm volatile("s_waitcnt lgkmcnt(0)" ::: "memory");
    __builtin_amdgcn_s_barrier();
    asm volatile("" ::: "memory");

    for (int j = 0; j < TPB; ++j) {
        // fp32 -> bf16 A-frags (compiler inserts counted vmcnt wait here)
        bf16x8 afr[4];
#pragma unroll
        for (int kb = 0; kb < 4; ++kb) {
            union { bf16x8 v; unsigned short h[8]; } u;
            u.h[0] = f2bf(pf[2 * kb].x);     u.h[1] = f2bf(pf[2 * kb].y);
            u.h[2] = f2bf(pf[2 * kb].z);     u.h[3] = f2bf(pf[2 * kb].w);
            u.h[4] = f2bf(pf[2 * kb + 1].x); u.h[5] = f2bf(pf[2 * kb + 1].y);
            u.h[6] = f2bf(pf[2 * kb + 1].z); u.h[7] = f2bf(pf[2 * kb + 1].w);
            afr[kb] = u.v;
        }

        // stage 1: U = W @ R2  (A from regs, B = R2T rows from LDS)
        f32x16 acc;
#pragma unroll
        for (int i = 0; i < 16; ++i) acc[i] = 0.0f;
#pragma unroll
        for (int kb = 0; kb < 4; ++kb) {
            int k0 = kb * 16 + lhi * 8;
            bf16x8 b = *(const bf16x8*)&R2Tl[n][k0];
            acc = __builtin_amdgcn_mfma_f32_32x32x16_bf16(afr[kb], b, acc, 0, 0, 0);
        }

        // C-layout (col=lane&31, row=(reg&3)+8*(reg>>2)+4*lhi) -> UT[col][row]
        unsigned short (*UT)[72] = UTl[j & 1];
#pragma unroll
        for (int g = 0; g < 4; ++g) {
            int kbase = wr + 8 * g + 4 * lhi;
            us4 v;
            v[0] = f2bf(acc[4 * g + 0]); v[1] = f2bf(acc[4 * g + 1]);
            v[2] = f2bf(acc[4 * g + 2]); v[3] = f2bf(acc[4 * g + 3]);
            *(us4*)&UT[n][kbase] = v;   // 2-way conflict only (free)
        }

        // prefetch next tile's A data (stays in flight across the raw barrier,
        // overlapping stage 2 + stores + next conversion)
        if (j + 1 < TPB) {
            const float* an = asrc + (size_t)(j + 1) * NHEADS * TILE_ELEMS;
#pragma unroll
            for (int kb = 0; kb < 4; ++kb) {
                pf[2 * kb]     = *(const float4*)(an + kb * 16);
                pf[2 * kb + 1] = *(const float4*)(an + kb * 16 + 4);
            }
        }

        // single barrier per tile: UT[j&1] visible. LDS-drain only (no vmcnt).
        // Safe: every wave's prior-parity UT reads were drained by its own
        // lgkmcnt(0) before this barrier.
        asm volatile("s_waitcnt lgkmcnt(0)" ::: "memory");
        __builtin_amdgcn_s_barrier();
        asm volatile("" ::: "memory");

        // stage 2: out = R1 @ U
        f32x16 acc2;
#pragma unroll
        for (int i = 0; i < 16; ++i) acc2[i] = 0.0f;
#pragma unroll
        for (int kb = 0; kb < 4; ++kb) {
            int k0 = kb * 16 + lhi * 8;
            bf16x8 a = *(const bf16x8*)&R1l[m][k0];
            bf16x8 b = *(const bf16x8*)&UT[n][k0];
            acc2 = __builtin_amdgcn_mfma_f32_32x32x16_bf16(a, b, acc2, 0, 0, 0);
        }

        // store fp32 tile: each store = 2 x 128B segments, fully coalesced
        float* otile = out + (tile0 + (size_t)j * NHEADS) * TILE_ELEMS;
#pragma unroll
        for (int g = 0; g < 4; ++g) {
#pragma unroll
            for (int q = 0; q < 4; ++q) {
                int rowl = 8 * g + 4 * lhi + q;
                otile[(size_t)(wr + rowl) * 64 + wc + l31] = acc2[4 * g + q];
            }
        }
    }
}

extern "C" void kernel_launch(void* const* d_in, const int* in_sizes, int n_in,
                              void* d_out, int out_size, void* d_ws, size_t ws_size,
                              hipStream_t stream) {
    const float* wkv     = (const float*)d_in[0];
    const float* p_left  = (const float*)d_in[1];
    const float* p_right = (const float*)d_in[2];
    float* out = (float*)d_out;

    unsigned short* ws_r1  = (unsigned short*)d_ws;           // 32*4096 bf16
    unsigned short* ws_r2t = ws_r1 + NHEADS * TILE_ELEMS;

    cayley_kernel<<<64, 256, 0, stream>>>(p_left, p_right, ws_r1, ws_r2t);

    int ntiles = in_sizes[0] / TILE_ELEMS;          // B*C = 16384
    rot_kernel<<<ntiles / TPB, 256, 0, stream>>>(wkv, ws_r1, ws_r2t, out);
}

// Round 2
// 473.841 us; speedup vs baseline: 1.0203x; 1.0203x over previous
//
#include <hip/hip_runtime.h>
#include <hip/hip_bf16.h>

// BilateralRotation: out[b,c] = R1[c] @ wkv[b,c] @ R2[c]
// R = Cayley(p) = (I - A)(I + A)^{-1}, A = 0.5(p - p^T)
// B=512, C=32, H=W=64. wkv/out fp32; compute in bf16 MFMA (abs threshold 0.108).
//
// R4: combine R0's fully-coalesced global loads (1 KB contiguous per wave per
// instr) with R1's NON-draining barriers (lgkmcnt(0)-only; prefetch loads stay
// in flight across both barriers). Single-buffered Wl/UTl, 2 raw barriers per
// tile, race-free by per-wave lgkm drains (see per-phase comments).
// nt hints on streaming wkv loads / out stores. TPB=16 -> grid 1024 = exactly
// 4 blocks/CU, one resident round.

#define NHEADS 32
#define TILE_ELEMS 4096   // 64*64
#define TPB 16            // wkv tiles per rot block

typedef __attribute__((ext_vector_type(8))) short bf16x8;     // MFMA A/B frag
typedef __attribute__((ext_vector_type(16))) float f32x16;    // MFMA C/D (32x32)
typedef __attribute__((ext_vector_type(4))) unsigned short us4;
typedef __attribute__((ext_vector_type(4))) float f32x4;

static __device__ __forceinline__ unsigned short f2bf(float f) {
    // native cast -> backend emits packed v_cvt_pk_bf16_f32 (RNE)
    return __builtin_bit_cast(unsigned short, __float2bfloat16(f));
}

static __device__ __forceinline__ us4 f4bf(f32x4 v) {
    us4 o;
    o[0] = f2bf(v[0]); o[1] = f2bf(v[1]); o[2] = f2bf(v[2]); o[3] = f2bf(v[3]);
    return o;
}

// ---------------------------------------------------------------------------
// Kernel 1: Cayley. 64 blocks (32 left -> R1 row-major, 32 right -> R2
// TRANSPOSED). Register-resident Gauss-Jordan: thread (row, sl) owns
// M[row][16sl..16sl+15] and N[...] in VGPRs. Per iter k, only row k's slices
// + column-k factors pass through double-buffered LDS -> 1 barrier/iter.
// M = I+A has SPD symmetric part -> no pivoting needed.
// ---------------------------------------------------------------------------
__global__ __launch_bounds__(256) void cayley_kernel(
    const float* __restrict__ p_left, const float* __restrict__ p_right,
    unsigned short* __restrict__ ws_r1, unsigned short* __restrict__ ws_r2t) {
    __shared__ float P[64][68];       // stride 68: float4-aligned rows
    __shared__ float frowM[2][64];
    __shared__ float frowN[2][64];
    __shared__ float fcol[2][64];
    __shared__ float dinv_l[64];

    const int t = threadIdx.x;
    const int side = blockIdx.x >> 5;
    const int c = blockIdx.x & 31;
    const float* p = (side ? p_right : p_left) + c * TILE_ELEMS;

    // load p row-major (coalesced float4)
    for (int i = 0; i < 4; ++i) {
        int f = t + 256 * i;            // float4 index 0..1023
        int r = f >> 4, c4 = f & 15;
        *(float4*)&P[r][c4 * 4] = ((const float4*)p)[f];
    }
    __syncthreads();

    const int row = t & 63;
    const int sl  = t >> 6;
    const int jb  = sl * 16;

    // M = I + A, N = I - A in registers
    float mreg[16], nreg[16];
#pragma unroll
    for (int jj = 0; jj < 16; ++jj) {
        int j = jb + jj;
        float a = 0.5f * (P[row][j] - P[j][row]);
        float e = (row == j) ? 1.0f : 0.0f;
        mreg[jj] = e + a;
        nreg[jj] = e - a;
    }

    // Gauss-Jordan to diagonal; N -> diag(M) * R
    int buf = 0;
    for (int k = 0; k < 64; ++k) {
        const int kb = k >> 4, kk = k & 15;
        if (row == k) {
#pragma unroll
            for (int jj = 0; jj < 16; ++jj) {
                frowM[buf][jb + jj] = mreg[jj];
                frowN[buf][jb + jj] = nreg[jj];
            }
        }
        if (sl == kb) fcol[buf][row] = mreg[kk];
        __syncthreads();
        // safe single barrier: double-buffered staging; iter k+2 writes to
        // parity(k) only after barrier k+1, which postdates all iter-k reads.
        float pinv = __builtin_amdgcn_rcpf(frowM[buf][k]);
        float f = fcol[buf][row] * pinv;
        if (row != k) {
#pragma unroll
            for (int jj = 0; jj < 16; ++jj) {
                mreg[jj] -= f * frowM[buf][jb + jj];
                nreg[jj] -= f * frowN[buf][jb + jj];
            }
        }
        buf ^= 1;
    }

    if (sl == (row >> 4)) dinv_l[row] = __builtin_amdgcn_rcpf(mreg[row & 15]);
    __syncthreads();
    const float dinv = dinv_l[row];

    if (side == 0) {
        unsigned short* dst = ws_r1 + c * TILE_ELEMS;
#pragma unroll
        for (int q4 = 0; q4 < 4; ++q4) {
            us4 v;
#pragma unroll
            for (int q = 0; q < 4; ++q) v[q] = f2bf(nreg[q4 * 4 + q] * dinv);
            *(us4*)&dst[row * 64 + jb + q4 * 4] = v;
        }
    } else {
        unsigned short* dst = ws_r2t + c * TILE_ELEMS;
#pragma unroll
        for (int jj = 0; jj < 16; ++jj)
            dst[(jb + jj) * 64 + row] = f2bf(nreg[jj] * dinv);  // transposed
    }
}

// ---------------------------------------------------------------------------
// Kernel 2: 1024 blocks; block = (head c, 16 consecutive b). 4 waves, each a
// 32x32 quadrant. Per tile, 3 phases / 2 raw barriers:
//   A: convert prefetched fp32 tile -> bf16, ds_write Wl; issue next-tile
//      prefetch (coalesced dwordx4, stays in flight across BOTH barriers);
//      lgkmcnt(0)+s_barrier.
//   B: stage 1  U = W @ R2 (A,B frags from LDS); UT write; lgkmcnt(0)+barrier.
//   C: stage 2  out = R1 @ U; nt fp32 stores.
// Race-freedom with SINGLE-buffered Wl/UTl and no vmcnt drain:
//   Wl: reads in B(j) are drained by each wave's own lgkmcnt(0) before
//       barrier2(j); writes for tile j+1 occur in A(j+1), after barrier2(j).
//   UTl: reads in C(j) are drained by the lgkmcnt(0) ending A(j+1), before
//       barrier1(j+1); writes for j+1 occur in B(j+1), after barrier1(j+1).
// LDS stride 72 shorts (144 B): b128 frag reads conflict-free. 36.9 KB LDS ->
// 4 blocks/CU, grid 1024 = one resident round.
// ---------------------------------------------------------------------------
__global__ __launch_bounds__(256, 4) void rot_kernel(
    const float* __restrict__ wkv,
    const unsigned short* __restrict__ ws_r1,
    const unsigned short* __restrict__ ws_r2t,
    float* __restrict__ out) {
    __shared__ unsigned short R1l[64][72];
    __shared__ unsigned short R2Tl[64][72];
    __shared__ unsigned short Wl[64][72];
    __shared__ unsigned short UTl[64][72];

    const int t = threadIdx.x;
    const int c = blockIdx.x & 31;
    const int bg = blockIdx.x >> 5;
    const size_t tile0 = (size_t)(bg * TPB) * NHEADS + c;   // flat (b,c) index

    // stage R1 / R2T once (bf16, coalesced 8B, L2-hot; keep cached - reused
    // by the 32 blocks sharing this head)
    {
        const us4* s1 = (const us4*)(ws_r1 + c * TILE_ELEMS);
        const us4* s2 = (const us4*)(ws_r2t + c * TILE_ELEMS);
        for (int i = 0; i < 4; ++i) {
            int f = t + 256 * i;
            int r = f >> 4, c4 = f & 15;
            *(us4*)&R1l[r][c4 * 4]  = s1[f];
            *(us4*)&R2Tl[r][c4 * 4] = s2[f];
        }
    }

    const int lane = t & 63;
    const int wave = t >> 6;
    const int l31 = lane & 31;
    const int lhi = lane >> 5;
    const int wr = (wave & 1) * 32;
    const int wc = (wave >> 1) * 32;
    const int m = wr + l31;
    const int n = wc + l31;

    // prefetch tile 0 into registers (fully coalesced: wave reads 1 KB
    // contiguous per instruction; nt = streaming, no L2 temporal reuse)
    f32x4 pf[4];
    {
        const f32x4* wt = (const f32x4*)(wkv + tile0 * TILE_ELEMS);
#pragma unroll
        for (int i = 0; i < 4; ++i)
            pf[i] = __builtin_nontemporal_load(&wt[t + 256 * i]);
    }

    for (int j = 0; j < TPB; ++j) {
        // ---- phase A: fp32 regs -> bf16 -> Wl (compiler inserts counted
        // vmcnt wait for pf here; older stores/loads unaffected)
#pragma unroll
        for (int i = 0; i < 4; ++i) {
            int f = t + 256 * i;
            int r = f >> 4, c4 = f & 15;
            *(us4*)&Wl[r][c4 * 4] = f4bf(pf[i]);
        }

        // issue next tile's prefetch: in flight across both raw barriers,
        // covering stage1 + stage2 + stores (~a full tile period)
        if (j + 1 < TPB) {
            const f32x4* wn = (const f32x4*)(wkv + (tile0 + (size_t)(j + 1) * NHEADS) * TILE_ELEMS);
#pragma unroll
            for (int i = 0; i < 4; ++i)
                pf[i] = __builtin_nontemporal_load(&wn[t + 256 * i]);
        }

        asm volatile("s_waitcnt lgkmcnt(0)" ::: "memory");
        __builtin_amdgcn_s_barrier();           // B1: Wl (+ first-iter R) visible
        __builtin_amdgcn_sched_barrier(0);

        // ---- phase B: U = W @ R2
        f32x16 acc;
#pragma unroll
        for (int i = 0; i < 16; ++i) acc[i] = 0.0f;
#pragma unroll
        for (int kb = 0; kb < 4; ++kb) {
            int k0 = kb * 16 + lhi * 8;
            bf16x8 a = *(const bf16x8*)&Wl[m][k0];
            bf16x8 b = *(const bf16x8*)&R2Tl[n][k0];
            acc = __builtin_amdgcn_mfma_f32_32x32x16_bf16(a, b, acc, 0, 0, 0);
        }
        // C-layout (col=lane&31, row=(reg&3)+8*(reg>>2)+4*lhi) -> UT[col][row]
#pragma unroll
        for (int g = 0; g < 4; ++g) {
            int kbase = wr + 8 * g + 4 * lhi;
            us4 v;
            v[0] = f2bf(acc[4 * g + 0]); v[1] = f2bf(acc[4 * g + 1]);
            v[2] = f2bf(acc[4 * g + 2]); v[3] = f2bf(acc[4 * g + 3]);
            *(us4*)&UTl[n][kbase] = v;   // 2-way conflict only (free)
        }

        asm volatile("s_waitcnt lgkmcnt(0)" ::: "memory");
        __builtin_amdgcn_s_barrier();           // B2: UTl visible; Wl reads drained
        __builtin_amdgcn_sched_barrier(0);

        // ---- phase C: out = R1 @ U
        f32x16 acc2;
#pragma unroll
        for (int i = 0; i < 16; ++i) acc2[i] = 0.0f;
#pragma unroll
        for (int kb = 0; kb < 4; ++kb) {
            int k0 = kb * 16 + lhi * 8;
            bf16x8 a = *(const bf16x8*)&R1l[m][k0];
            bf16x8 b = *(const bf16x8*)&UTl[n][k0];
            acc2 = __builtin_amdgcn_mfma_f32_32x32x16_bf16(a, b, acc2, 0, 0, 0);
        }

        // fp32 stores: each instr = 2 x 128B full-line segments, coalesced;
        // nt = streaming store, don't displace L2
        float* otile = out + (tile0 + (size_t)j * NHEADS) * TILE_ELEMS;
#pragma unroll
        for (int g = 0; g < 4; ++g) {
#pragma unroll
            for (int q = 0; q < 4; ++q) {
                int rowl = 8 * g + 4 * lhi + q;
                __builtin_nontemporal_store(
                    acc2[4 * g + q],
                    &otile[(size_t)(wr + rowl) * 64 + wc + l31]);
            }
        }
    }
}

extern "C" void kernel_launch(void* const* d_in, const int* in_sizes, int n_in,
                              void* d_out, int out_size, void* d_ws, size_t ws_size,
                              hipStream_t stream) {
    const float* wkv     = (const float*)d_in[0];
    const float* p_left  = (const float*)d_in[1];
    const float* p_right = (const float*)d_in[2];
    float* out = (float*)d_out;

    unsigned short* ws_r1  = (unsigned short*)d_ws;           // 32*4096 bf16
    unsigned short* ws_r2t = ws_r1 + NHEADS * TILE_ELEMS;

    cayley_kernel<<<64, 256, 0, stream>>>(p_left, p_right, ws_r1, ws_r2t);

    int ntiles = in_sizes[0] / TILE_ELEMS;          // B*C = 16384
    rot_kernel<<<ntiles / TPB, 256, 0, stream>>>(wkv, ws_r1, ws_r2t, out);
}